// Round 15
// baseline (129.555 us; speedup 1.0000x reference)
//
#include <hip/hip_runtime.h>
#include <hip/hip_bf16.h>

// Deformable 2D conv, split-kernel. B=8 H=128 W=128 C=64 F=128 K=3.
// KA blocks 0..1023: offsets conv, LDS-staged. Block = 2 rows x 64 cols
//   (128 px), 384 thr = 6 waves. Stage x rows i0-1..i0+2, cols j0-1..j0+64
//   fp32 XOR-swizzled (coalesced loads). Wave = (pixel-row, p) pair: p is
//   wave-uniform (readfirstlane -> oW via scalar cache), lane = pixel.
//   ds_read_b128 conflict-free (XOR spreads row*256B), 1728 FMA, 9 chains.
//   LDS partial reduce over p. XCD-swizzled (batch == XCD).
// KA blocks 1024..1215: cW -> cWb bf16 pack, MFMA frag order [ks][q4][f][jj].
// KB main: R13 structure + scalar-component asm liveness pin so the 6
//   gather loads stay batched in flight.
// Fallback (small ws): fused kernel.
//
// MFMA 16x16x32 bf16 (m89/m91): A row=lane&15, k=8*(lane>>4)+j; B col same;
// D col=lane&15, row=4*(lane>>4)+reg.
// NOTE: offsets must stay fp32 (bf16 offsets flip floor() at the clamp
// discontinuities -> R5 failed at 2.39).

typedef __attribute__((ext_vector_type(8))) short short8;
typedef __attribute__((ext_vector_type(4))) float f32x4;

#define CWB_BYTES (18 * 4 * 128 * 8 * 2)  // 147456
#define OFFS_OFF  CWB_BYTES
#define OFFS_BYTES (131072 * 9 * 4)       // 4718592
#define WS_SPLIT  (CWB_BYTES + OFFS_BYTES)

__device__ __forceinline__ unsigned short f2bf(float f) {  // RNE
  union { float f; unsigned u; } v; v.f = f;
  unsigned r = v.u + 0x7fffu + ((v.u >> 16) & 1u);
  return (unsigned short)(r >> 16);
}

__device__ __forceinline__ unsigned pk2bf(float a, float b) {  // v_cvt_pk RNE
  __hip_bfloat162 h = __float22bfloat162_rn(make_float2(a, b));
  union { __hip_bfloat162 h; unsigned u; } c; c.h = h;
  return c.u;
}

// ---- KA: offsets (blocks 0..1023, LDS-staged) + pack (1024..1215) --------
__global__ __launch_bounds__(384) void offsets_pack_kernel(
    const float* __restrict__ x, const float* __restrict__ oW,
    const float* __restrict__ ob, const float* __restrict__ cW,
    float* __restrict__ offs, unsigned short* __restrict__ cWb) {
  const int hw = blockIdx.x;
  const int tid = threadIdx.x;
  if (hw >= 1024) {  // pack: t = k*128 + f
    const int t = (hw - 1024) * 384 + tid;
    if (t < 73728) {
      const int k = t >> 7, f = t & 127;
      const int ks = k >> 5, q4 = (k >> 3) & 3, jj = k & 7;
      cWb[(size_t)(((ks * 4 + q4) * 128 + f) * 8 + jj)] = f2bf(cW[t]);
    }
    return;
  }
  __shared__ __align__(16) char xls[4 * 66 * 64 * 4];  // 67584 B
  float* const xpart = (float*)xls;  // reused for partials after compute

  const int logical = ((hw & 7) << 7) | (hw >> 3);  // XCD k -> batch k
  const int b = logical >> 7;
  const int rp = (logical >> 1) & 63;
  const int half = logical & 1;
  const int i0 = rp << 1;    // rows i0, i0+1
  const int j0 = half << 6;  // cols j0..j0+63
  const float* xb = x + ((size_t)b << 20);

  // ---- stage rows i0-1..i0+2, cols j0-1..j0+64, zero-padded, coalesced ----
  for (int it = tid; it < 4 * 66 * 16; it += 384) {
    const int c4 = it & 15;
    const int rc = it >> 4;  // row index rr*66+cc, 0..263
    const int cc = rc % 66;
    const int rr = rc / 66;
    const int grow = i0 + rr - 1;
    const int gcol = j0 + cc - 1;
    float4 v = make_float4(0.f, 0.f, 0.f, 0.f);
    if (grow >= 0 && grow <= 127 && gcol >= 0 && gcol <= 127)
      v = ((const float4*)(xb + (((grow << 7) + gcol) << 6)))[c4];
    const int boff = (rc * 256 + c4 * 16) ^ ((rc & 7) << 4);
    *(float4*)(xls + boff) = v;
  }
  __syncthreads();

  // ---- compute: wave w -> (ir = w/3, p = w%3); lane = pixel col ----
  const int lane = tid & 63;
  const int w = tid >> 6;  // 0..5
  const int ir = (w >= 3) ? 1 : 0;
  const int p = __builtin_amdgcn_readfirstlane(w - ir * 3);
  float acc[9];
#pragma unroll
  for (int t = 0; t < 9; ++t) acc[t] = 0.f;
#pragma unroll
  for (int q = 0; q < 3; ++q) {
    const int row = (ir + p) * 66 + lane + q;  // staged row
    const float* wq = oW + (size_t)(p * 3 + q) * 576;  // scalar (p uniform)
    for (int c4 = 0; c4 < 16; ++c4) {
      const int boff = (row * 256 + c4 * 16) ^ ((row & 7) << 4);
      const float4 v = *(const float4*)(xls + boff);
      const float* wc = wq + c4 * 36;
#pragma unroll
      for (int t = 0; t < 9; ++t) acc[t] += v.x * wc[t];
#pragma unroll
      for (int t = 0; t < 9; ++t) acc[t] += v.y * wc[9 + t];
#pragma unroll
      for (int t = 0; t < 9; ++t) acc[t] += v.z * wc[18 + t];
#pragma unroll
      for (int t = 0; t < 9; ++t) acc[t] += v.w * wc[27 + t];
    }
  }
  __syncthreads();  // all staging reads done; reuse xls for partials
#pragma unroll
  for (int t = 0; t < 9; ++t) xpart[(w * 64 + lane) * 9 + t] = acc[t];
  __syncthreads();

  // ---- reduce over p and write (coalesced: r enumerates px*9+t) ----
  for (int r = tid; r < 1152; r += 384) {
    const int px = r / 9;
    const int t = r - px * 9;
    const int irx = px >> 6;
    const int pc = px & 63;
    const float s = xpart[((irx * 3 + 0) * 64 + pc) * 9 + t] +
                    xpart[((irx * 3 + 1) * 64 + pc) * 9 + t] +
                    xpart[((irx * 3 + 2) * 64 + pc) * 9 + t] + ob[t];
    offs[((size_t)(((b << 7) | (i0 + irx)) << 7) | (j0 + pc)) * 9 + t] = s;
  }
}

// ---- KB: gather + MFMA main conv -----------------------------------------
__global__ __launch_bounds__(512, 4) void main_kernel(
    const float* __restrict__ x, const float* __restrict__ offs,
    const float* __restrict__ cb, float* __restrict__ out,
    const unsigned short* __restrict__ cWb) {
  __shared__ __align__(16) char lds[32 * 576 * 2];  // 36864 B
  __shared__ float offw[288];   // w1 per (pix,tap)
  __shared__ int2 gmeta[288];   // g0,g1 byte offsets per (pix,tap)

  const int tid = threadIdx.x;
  const int hwbid = blockIdx.x;
  const int bid = ((hwbid & 7) << 9) | (hwbid >> 3);  // XCD k -> batch k
  const int j0 = (bid & 3) << 5;
  const int i = (bid >> 2) & 127;
  const int b = bid >> 9;
  const float* xb = x + ((size_t)b << 20);

  const int lane = tid & 63;
  const int wv = tid >> 6;

  // ---- meta: per-(pix,tap) gather metadata, computed once ----
  if (tid < 288) {
    const int pix = (tid * 456) >> 12;  // exact /9 for tid<288
    const int tap = tid - pix * 9;
    const size_t base9 = ((size_t)(((b << 7) | i) << 7) | j0) * 9;
    const float off = offs[base9 + tid];
    const int p = tap / 3;
    const int q = tap - p * 3;
    int yy = i + p - 1;
    yy = yy < 0 ? 0 : (yy > 127 ? 127 : yy);
    const float xf = (float)(j0 + pix + q - 1) + off;
    const float x0f = floorf(xf);
    const float w1 = xf - x0f;  // weight from UNclipped floor (matches ref)
    int x0i = (int)x0f;
    x0i = x0i < 0 ? 0 : (x0i > 127 ? 127 : x0i);
    const int x1i = (x0i + 1 > 127) ? 127 : x0i + 1;
    gmeta[tid].x = ((yy << 7) + x0i) << 8;  // byte offset of 64-float row
    gmeta[tid].y = ((yy << 7) + x1i) << 8;
    offw[tid] = w1;
  }
  __syncthreads();

  // ---- Phase 1: gather; 3 batches x 6 loads, liveness-pinned ----
#pragma unroll
  for (int batch = 0; batch < 3; ++batch) {
    int a0_[3], a1_[3], sb[3];
    float sw1[3];
#pragma unroll
    for (int s = 0; s < 3; ++s) {
      const int idx = tid + (batch * 3 + s) * 512;
      const int c4 = idx & 15;
      const int pair = idx >> 4;
      const int2 g = gmeta[pair];
      sw1[s] = offw[pair];
      a0_[s] = g.x + (c4 << 4);
      a1_[s] = g.y + (c4 << 4);
      const int pix8 = ((pair * 456) >> 12) & 7;
      sb[s] = ((pair << 7) + (c4 << 3)) ^ (pix8 << 4);
    }
    float4 s0[3], s1[3];
#pragma unroll
    for (int s = 0; s < 3; ++s) {
      s0[s] = *(const float4*)((const char*)xb + a0_[s]);
      s1[s] = *(const float4*)((const char*)xb + a1_[s]);
    }
    // force all 6 loads simultaneously issued/live: pin one scalar component
    // per dwordx4 (the load writes all 4 regs in one instruction), then
    // forbid reordering across this point.
    asm volatile("" :: "v"(s0[0].x), "v"(s0[1].x), "v"(s0[2].x),
                       "v"(s1[0].x), "v"(s1[1].x), "v"(s1[2].x));
    __builtin_amdgcn_sched_barrier(0);
#pragma unroll
    for (int s = 0; s < 3; ++s) {
      const float w1 = sw1[s];
      uint2 pk;
      pk.x = pk2bf(s0[s].x + w1 * (s1[s].x - s0[s].x),
                   s0[s].y + w1 * (s1[s].y - s0[s].y));
      pk.y = pk2bf(s0[s].z + w1 * (s1[s].z - s0[s].z),
                   s0[s].w + w1 * (s1[s].w - s0[s].w));
      *(uint2*)(lds + sb[s]) = pk;
    }
  }
  __syncthreads();

  // ---- Phase 2: MFMA, swapped operands. Wave w: m=w&1, f0=(w>>1)*32 ----
  const int m = wv & 1;
  const int f0 = (wv >> 1) << 5;
  const int colf = lane & 15;
  const int q4 = lane >> 4;
  const int pixr = m * 16 + colf;
  f32x4 a0 = {0.f, 0.f, 0.f, 0.f}, a1 = a0;
  short8 bf0, bf1;
  {
    const unsigned short* wb = cWb + (size_t)((q4 * 128 + f0 + colf) * 8);
    bf0 = *(const short8*)wb;
    bf1 = *(const short8*)(wb + 128);
  }
  for (int ks = 0; ks < 18; ++ks) {
    const int aoff = (pixr * 1152 + ks * 64 + q4 * 16) ^ ((pixr & 7) << 4);
    const short8 af = *(const short8*)(lds + aoff);
    short8 nb0, nb1;
    if (ks < 17) {
      const unsigned short* wn =
          cWb + (size_t)((((ks + 1) * 4 + q4) * 128 + f0 + colf) * 8);
      nb0 = *(const short8*)wn;
      nb1 = *(const short8*)(wn + 128);
    }
    a0 = __builtin_amdgcn_mfma_f32_16x16x32_bf16(bf0, af, a0, 0, 0, 0);
    a1 = __builtin_amdgcn_mfma_f32_16x16x32_bf16(bf1, af, a1, 0, 0, 0);
    if (ks < 17) { bf0 = nb0; bf1 = nb1; }
  }
  __syncthreads();  // phase-2 LDS reads done; reuse lds for out staging

  // ---- Epilogue: stage [32 pix][132] fp32, then coalesced stores ----
  float* const outS = (float*)lds;
  {
    const float4 cb0 = *(const float4*)(cb + f0 + q4 * 4);
    const float4 cb1 = *(const float4*)(cb + f0 + 16 + q4 * 4);
    float4 r0, r1;
    r0.x = a0[0] + cb0.x; r0.y = a0[1] + cb0.y;
    r0.z = a0[2] + cb0.z; r0.w = a0[3] + cb0.w;
    r1.x = a1[0] + cb1.x; r1.y = a1[1] + cb1.y;
    r1.z = a1[2] + cb1.z; r1.w = a1[3] + cb1.w;
    *(float4*)(outS + pixr * 132 + f0 + q4 * 4) = r0;
    *(float4*)(outS + pixr * 132 + f0 + 16 + q4 * 4) = r1;
  }
  __syncthreads();
  float4* og = (float4*)(out + (((size_t)((b << 14) | (i << 7) | j0)) << 7));
#pragma unroll
  for (int r = 0; r < 2; ++r) {
    const int f4i = r * 512 + tid;
    const int pp = f4i >> 5, ff = f4i & 31;
    og[pp * 32 + ff] = *(const float4*)(outS + pp * 132 + ff * 4);
  }
}

// ---- Fallback: fused kernel (small ws) ----
__global__ __launch_bounds__(512, 8) void fused_deform_kernel(
    const float* __restrict__ x, const float* __restrict__ oW,
    const float* __restrict__ ob, const float* __restrict__ cW,
    const float* __restrict__ cb, float* __restrict__ out) {
  __shared__ __align__(16) char lds[32 * 576 * 2];
  __shared__ float offs_s[288];
  float* const xtile = (float*)lds;  // [102 rows][stride 68]

  const int tid = threadIdx.x;
  const int bid = blockIdx.x;
  const int j0 = (bid & 3) << 5;
  const int i = (bid >> 2) & 127;
  const int b = bid >> 9;
  const float* xb = x + ((size_t)b << 20);
  const int lane = tid & 63;
  const int wv = tid >> 6;

  for (int t = tid; t < 3 * 34 * 16; t += 512) {
    const int c4 = t & 15;
    const int cc = (t >> 4) % 34;
    const int r = (t >> 4) / 34;
    const int row = i + r - 1;
    const int col = j0 + cc - 1;
    float4 v = make_float4(0.f, 0.f, 0.f, 0.f);
    if (row >= 0 && row <= 127 && col >= 0 && col <= 127)
      v = ((const float4*)(xb + (((row << 7) + col) << 6)))[c4];
    *(float4*)(xtile + (r * 34 + cc) * 68 + c4 * 4) = v;
  }
  __syncthreads();

  for (int t = tid; t < 576; t += 512) {
    const int half = t & 1;
    const int item = t >> 1;
    const int ochan = item % 9;
    const int pix = item / 9;
    const int c4base = half << 3;
    f32x4 acc = {0.f, 0.f, 0.f, 0.f};
#pragma unroll
    for (int pq = 0; pq < 9; ++pq) {
      const int p = pq / 3, q = pq - p * 3;
      const float4* xr = (const float4*)(xtile + (p * 34 + pix + q) * 68) + c4base;
      const float* wr = oW + (size_t)(pq * 64 + c4base * 4) * 9 + ochan;
#pragma unroll
      for (int c4 = 0; c4 < 8; ++c4) {
        const float4 v = xr[c4];
        acc.x += v.x * wr[(c4 * 4 + 0) * 9];
        acc.y += v.y * wr[(c4 * 4 + 1) * 9];
        acc.z += v.z * wr[(c4 * 4 + 2) * 9];
        acc.w += v.w * wr[(c4 * 4 + 3) * 9];
      }
    }
    float s = (acc.x + acc.y) + (acc.z + acc.w);
    s += __shfl_xor(s, 1);
    if (!half) offs_s[item] = s + ob[ochan];
  }
  __syncthreads();

  for (int it = tid; it < 32 * 9 * 16; it += 512) {
    const int c4 = it & 15;
    const int tmp = it >> 4;
    const int tap = tmp % 9;
    const int pix = tmp / 9;
    const int j = j0 + pix;
    const float off = offs_s[pix * 9 + tap];
    const int p = tap / 3;
    const int q = tap - p * 3;
    int yy = i + p - 1;
    yy = yy < 0 ? 0 : (yy > 127 ? 127 : yy);
    const float xf = (float)(j + q - 1) + off;
    const float x0f = floorf(xf);
    const float w1 = xf - x0f;
    int x0i = (int)x0f;
    x0i = x0i < 0 ? 0 : (x0i > 127 ? 127 : x0i);
    const int x1i = (x0i + 1 > 127) ? 127 : x0i + 1;
    const float4 s0 = ((const float4*)(xb + (((yy << 7) + x0i) << 6)))[c4];
    const float4 s1 = ((const float4*)(xb + (((yy << 7) + x1i) << 6)))[c4];
    const float w0 = 1.0f - w1;
    const int boff = (pix * 1152 + tap * 128 + c4 * 8) ^ ((pix & 7) << 4);
    uint2 pk;
    pk.x = (unsigned)f2bf(s0.x * w0 + s1.x * w1) |
           ((unsigned)f2bf(s0.y * w0 + s1.y * w1) << 16);
    pk.y = (unsigned)f2bf(s0.z * w0 + s1.z * w1) |
           ((unsigned)f2bf(s0.w * w0 + s1.w * w1) << 16);
    *(uint2*)(lds + boff) = pk;
  }
  __syncthreads();

  const int m = wv & 1;
  const int f0 = (wv >> 1) << 5;
  const int colf = lane & 15;
  const int q4 = lane >> 4;
  const int pixr = m * 16 + colf;
  f32x4 a0 = {0.f, 0.f, 0.f, 0.f}, a1 = a0;
  for (int ks = 0; ks < 18; ++ks) {
    const int aoff = (pixr * 1152 + ks * 64 + q4 * 16) ^ ((pixr & 7) << 4);
    const short8 af = *(const short8*)(lds + aoff);
    short8 bf0, bf1;
    const float* wp = cW + (size_t)(ks * 32 + q4 * 8) * 128 + f0 + colf;
#pragma unroll
    for (int jj = 0; jj < 8; ++jj) bf0[jj] = (short)f2bf(wp[jj * 128]);
#pragma unroll
    for (int jj = 0; jj < 8; ++jj) bf1[jj] = (short)f2bf(wp[jj * 128 + 16]);
    a0 = __builtin_amdgcn_mfma_f32_16x16x32_bf16(bf0, af, a0, 0, 0, 0);
    a1 = __builtin_amdgcn_mfma_f32_16x16x32_bf16(bf1, af, a1, 0, 0, 0);
  }

  const float cb0s = cb[f0 + colf];
  const float cb1s = cb[f0 + 16 + colf];
  float* obase = out + (((size_t)((b << 14) | (i << 7) | j0)) << 7);
#pragma unroll
  for (int reg = 0; reg < 4; ++reg) {
    float* r = obase + (size_t)(m * 16 + q4 * 4 + reg) * 128;
    r[f0 + colf] = a0[reg] + cb0s;
    r[f0 + 16 + colf] = a1[reg] + cb1s;
  }
}

extern "C" void kernel_launch(void* const* d_in, const int* in_sizes, int n_in,
                              void* d_out, int out_size, void* d_ws, size_t ws_size,
                              hipStream_t stream) {
  const float* x = (const float*)d_in[0];
  const float* oW = (const float*)d_in[1];
  const float* ob = (const float*)d_in[2];
  const float* cW = (const float*)d_in[3];
  const float* cb = (const float*)d_in[4];
  float* out = (float*)d_out;

  if (ws_size >= WS_SPLIT) {
    unsigned short* cWb = (unsigned short*)d_ws;
    float* offs = (float*)((char*)d_ws + OFFS_OFF);
    hipLaunchKernelGGL(offsets_pack_kernel, dim3(1216), dim3(384), 0, stream,
                       x, oW, ob, cW, offs, cWb);
    hipLaunchKernelGGL(main_kernel, dim3(4096), dim3(512), 0, stream,
                       x, offs, cb, out, cWb);
  } else {
    hipLaunchKernelGGL(fused_deform_kernel, dim3(4096), dim3(512), 0, stream,
                       x, oW, ob, cW, cb, out);
  }
}

// Round 16
// 115.013 us; speedup vs baseline: 1.1264x; 1.1264x over previous
//
#include <hip/hip_runtime.h>
#include <hip/hip_bf16.h>

// Deformable 2D conv, split-kernel. B=8 H=128 W=128 C=64 F=128 K=3.
// KA: blocks 0..511 = offsets conv (R11-exact, proven ~46us: 1 thread/pixel,
//     wave-uniform oW reads via scalar cache, 16 x-loads hoisted per tap),
//     XCD-swizzled; blocks 512..799 = cW->cWb bf16 pack [ks][q4][f][jj].
// KB: main (R15-exact, proven ~45us): block = 32 pixels of one row, 512 thr.
//     meta-once -> LDS; gather 3x3 batches with scalar-component asm
//     liveness pin + sched_barrier (keeps 6 loads in flight); v_cvt_pk bf16
//     pack; XOR-swizzled smpB; MFMA 16x16x32 swapped operands + B prefetch;
//     LDS-staged coalesced epilogue.
// Fallback (small ws): fused kernel.
//
// MFMA 16x16x32 bf16 (m89/m91): A row=lane&15, k=8*(lane>>4)+j; B col same;
// D col=lane&15, row=4*(lane>>4)+reg.
// NOTE: offsets must stay fp32 (bf16 offsets flip floor() at the clamp
// discontinuities -> R5 failed at 2.39).

typedef __attribute__((ext_vector_type(8))) short short8;
typedef __attribute__((ext_vector_type(4))) float f32x4;

#define CWB_BYTES (18 * 4 * 128 * 8 * 2)  // 147456
#define OFFS_OFF  CWB_BYTES
#define OFFS_BYTES (131072 * 9 * 4)       // 4718592
#define WS_SPLIT  (CWB_BYTES + OFFS_BYTES)

__device__ __forceinline__ unsigned short f2bf(float f) {  // RNE
  union { float f; unsigned u; } v; v.f = f;
  unsigned r = v.u + 0x7fffu + ((v.u >> 16) & 1u);
  return (unsigned short)(r >> 16);
}

__device__ __forceinline__ unsigned pk2bf(float a, float b) {  // v_cvt_pk RNE
  __hip_bfloat162 h = __float22bfloat162_rn(make_float2(a, b));
  union { __hip_bfloat162 h; unsigned u; } c; c.h = h;
  return c.u;
}

// ---- KA: offsets (blocks 0..511, R11-exact) + pack (512..799) ------------
__global__ __launch_bounds__(256) void offsets_pack_kernel(
    const float* __restrict__ x, const float* __restrict__ oW,
    const float* __restrict__ ob, const float* __restrict__ cW,
    float* __restrict__ offs, unsigned short* __restrict__ cWb) {
  const int hw = blockIdx.x;
  if (hw >= 512) {  // pack: t = k*128 + f
    const int t = (hw - 512) * 256 + threadIdx.x;
    if (t < 73728) {
      const int k = t >> 7, f = t & 127;
      const int ks = k >> 5, q4 = (k >> 3) & 3, jj = k & 7;
      cWb[(size_t)(((ks * 4 + q4) * 128 + f) * 8 + jj)] = f2bf(cW[t]);
    }
    return;
  }
  const int logical = ((hw & 7) << 6) | (hw >> 3);  // XCD k -> batch k
  const int pix = logical * 256 + threadIdx.x;      // 0..131071
  const int j = pix & 127;
  const int i = (pix >> 7) & 127;
  const int b = pix >> 14;
  float acc[9];
#pragma unroll
  for (int t = 0; t < 9; ++t) acc[t] = ob[t];
  const float* xb = x + ((size_t)b << 20);
#pragma unroll
  for (int p = 0; p < 3; ++p) {
    const int yy = i + p - 1;
    if (yy < 0 || yy > 127) continue;  // zero padding
#pragma unroll
    for (int q = 0; q < 3; ++q) {
      const int xx = j + q - 1;
      if (xx < 0 || xx > 127) continue;
      const float4* xp = (const float4*)(xb + (((yy << 7) + xx) << 6));
      // hoist the whole 64-channel row: 16 loads in flight
      float4 v[16];
#pragma unroll
      for (int c4 = 0; c4 < 16; ++c4) v[c4] = xp[c4];
      const float* wp = oW + (p * 3 + q) * 576;  // wave-uniform -> sK$
#pragma unroll
      for (int c4 = 0; c4 < 16; ++c4) {
        const float* w = wp + c4 * 36;
#pragma unroll
        for (int t = 0; t < 9; ++t) acc[t] += v[c4].x * w[t];
#pragma unroll
        for (int t = 0; t < 9; ++t) acc[t] += v[c4].y * w[9 + t];
#pragma unroll
        for (int t = 0; t < 9; ++t) acc[t] += v[c4].z * w[18 + t];
#pragma unroll
        for (int t = 0; t < 9; ++t) acc[t] += v[c4].w * w[27 + t];
      }
    }
  }
  float* op = offs + (size_t)pix * 9;
#pragma unroll
  for (int t = 0; t < 9; ++t) op[t] = acc[t];
}

// ---- KB: gather + MFMA main conv (R15-exact) -----------------------------
__global__ __launch_bounds__(512, 4) void main_kernel(
    const float* __restrict__ x, const float* __restrict__ offs,
    const float* __restrict__ cb, float* __restrict__ out,
    const unsigned short* __restrict__ cWb) {
  __shared__ __align__(16) char lds[32 * 576 * 2];  // 36864 B
  __shared__ float offw[288];   // w1 per (pix,tap)
  __shared__ int2 gmeta[288];   // g0,g1 byte offsets per (pix,tap)

  const int tid = threadIdx.x;
  const int hwbid = blockIdx.x;
  const int bid = ((hwbid & 7) << 9) | (hwbid >> 3);  // XCD k -> batch k
  const int j0 = (bid & 3) << 5;
  const int i = (bid >> 2) & 127;
  const int b = bid >> 9;
  const float* xb = x + ((size_t)b << 20);

  const int lane = tid & 63;
  const int wv = tid >> 6;

  // ---- meta: per-(pix,tap) gather metadata, computed once ----
  if (tid < 288) {
    const int pix = (tid * 456) >> 12;  // exact /9 for tid<288
    const int tap = tid - pix * 9;
    const size_t base9 = ((size_t)(((b << 7) | i) << 7) | j0) * 9;
    const float off = offs[base9 + tid];
    const int p = tap / 3;
    const int q = tap - p * 3;
    int yy = i + p - 1;
    yy = yy < 0 ? 0 : (yy > 127 ? 127 : yy);
    const float xf = (float)(j0 + pix + q - 1) + off;
    const float x0f = floorf(xf);
    const float w1 = xf - x0f;  // weight from UNclipped floor (matches ref)
    int x0i = (int)x0f;
    x0i = x0i < 0 ? 0 : (x0i > 127 ? 127 : x0i);
    const int x1i = (x0i + 1 > 127) ? 127 : x0i + 1;
    gmeta[tid].x = ((yy << 7) + x0i) << 8;  // byte offset of 64-float row
    gmeta[tid].y = ((yy << 7) + x1i) << 8;
    offw[tid] = w1;
  }
  __syncthreads();

  // ---- Phase 1: gather; 3 batches x 6 loads, liveness-pinned ----
#pragma unroll
  for (int batch = 0; batch < 3; ++batch) {
    int a0_[3], a1_[3], sb[3];
    float sw1[3];
#pragma unroll
    for (int s = 0; s < 3; ++s) {
      const int idx = tid + (batch * 3 + s) * 512;
      const int c4 = idx & 15;
      const int pair = idx >> 4;
      const int2 g = gmeta[pair];
      sw1[s] = offw[pair];
      a0_[s] = g.x + (c4 << 4);
      a1_[s] = g.y + (c4 << 4);
      const int pix8 = ((pair * 456) >> 12) & 7;
      sb[s] = ((pair << 7) + (c4 << 3)) ^ (pix8 << 4);
    }
    float4 s0[3], s1[3];
#pragma unroll
    for (int s = 0; s < 3; ++s) {
      s0[s] = *(const float4*)((const char*)xb + a0_[s]);
      s1[s] = *(const float4*)((const char*)xb + a1_[s]);
    }
    // force all 6 loads simultaneously issued/live (one component pins the
    // whole dwordx4), then forbid reordering across this point.
    asm volatile("" :: "v"(s0[0].x), "v"(s0[1].x), "v"(s0[2].x),
                       "v"(s1[0].x), "v"(s1[1].x), "v"(s1[2].x));
    __builtin_amdgcn_sched_barrier(0);
#pragma unroll
    for (int s = 0; s < 3; ++s) {
      const float w1 = sw1[s];
      uint2 pk;
      pk.x = pk2bf(s0[s].x + w1 * (s1[s].x - s0[s].x),
                   s0[s].y + w1 * (s1[s].y - s0[s].y));
      pk.y = pk2bf(s0[s].z + w1 * (s1[s].z - s0[s].z),
                   s0[s].w + w1 * (s1[s].w - s0[s].w));
      *(uint2*)(lds + sb[s]) = pk;
    }
  }
  __syncthreads();

  // ---- Phase 2: MFMA, swapped operands. Wave w: m=w&1, f0=(w>>1)*32 ----
  const int m = wv & 1;
  const int f0 = (wv >> 1) << 5;
  const int colf = lane & 15;
  const int q4 = lane >> 4;
  const int pixr = m * 16 + colf;
  f32x4 a0 = {0.f, 0.f, 0.f, 0.f}, a1 = a0;
  short8 bf0, bf1;
  {
    const unsigned short* wb = cWb + (size_t)((q4 * 128 + f0 + colf) * 8);
    bf0 = *(const short8*)wb;
    bf1 = *(const short8*)(wb + 128);
  }
  for (int ks = 0; ks < 18; ++ks) {
    const int aoff = (pixr * 1152 + ks * 64 + q4 * 16) ^ ((pixr & 7) << 4);
    const short8 af = *(const short8*)(lds + aoff);
    short8 nb0, nb1;
    if (ks < 17) {
      const unsigned short* wn =
          cWb + (size_t)((((ks + 1) * 4 + q4) * 128 + f0 + colf) * 8);
      nb0 = *(const short8*)wn;
      nb1 = *(const short8*)(wn + 128);
    }
    a0 = __builtin_amdgcn_mfma_f32_16x16x32_bf16(bf0, af, a0, 0, 0, 0);
    a1 = __builtin_amdgcn_mfma_f32_16x16x32_bf16(bf1, af, a1, 0, 0, 0);
    if (ks < 17) { bf0 = nb0; bf1 = nb1; }
  }
  __syncthreads();  // phase-2 LDS reads done; reuse lds for out staging

  // ---- Epilogue: stage [32 pix][132] fp32, then coalesced stores ----
  float* const outS = (float*)lds;
  {
    const float4 cb0 = *(const float4*)(cb + f0 + q4 * 4);
    const float4 cb1 = *(const float4*)(cb + f0 + 16 + q4 * 4);
    float4 r0, r1;
    r0.x = a0[0] + cb0.x; r0.y = a0[1] + cb0.y;
    r0.z = a0[2] + cb0.z; r0.w = a0[3] + cb0.w;
    r1.x = a1[0] + cb1.x; r1.y = a1[1] + cb1.y;
    r1.z = a1[2] + cb1.z; r1.w = a1[3] + cb1.w;
    *(float4*)(outS + pixr * 132 + f0 + q4 * 4) = r0;
    *(float4*)(outS + pixr * 132 + f0 + 16 + q4 * 4) = r1;
  }
  __syncthreads();
  float4* og = (float4*)(out + (((size_t)((b << 14) | (i << 7) | j0)) << 7));
#pragma unroll
  for (int r = 0; r < 2; ++r) {
    const int f4i = r * 512 + tid;
    const int pp = f4i >> 5, ff = f4i & 31;
    og[pp * 32 + ff] = *(const float4*)(outS + pp * 132 + ff * 4);
  }
}

// ---- Fallback: fused kernel (small ws) ----
__global__ __launch_bounds__(512, 8) void fused_deform_kernel(
    const float* __restrict__ x, const float* __restrict__ oW,
    const float* __restrict__ ob, const float* __restrict__ cW,
    const float* __restrict__ cb, float* __restrict__ out) {
  __shared__ __align__(16) char lds[32 * 576 * 2];
  __shared__ float offs_s[288];
  float* const xtile = (float*)lds;  // [102 rows][stride 68]

  const int tid = threadIdx.x;
  const int bid = blockIdx.x;
  const int j0 = (bid & 3) << 5;
  const int i = (bid >> 2) & 127;
  const int b = bid >> 9;
  const float* xb = x + ((size_t)b << 20);
  const int lane = tid & 63;
  const int wv = tid >> 6;

  for (int t = tid; t < 3 * 34 * 16; t += 512) {
    const int c4 = t & 15;
    const int cc = (t >> 4) % 34;
    const int r = (t >> 4) / 34;
    const int row = i + r - 1;
    const int col = j0 + cc - 1;
    float4 v = make_float4(0.f, 0.f, 0.f, 0.f);
    if (row >= 0 && row <= 127 && col >= 0 && col <= 127)
      v = ((const float4*)(xb + (((row << 7) + col) << 6)))[c4];
    *(float4*)(xtile + (r * 34 + cc) * 68 + c4 * 4) = v;
  }
  __syncthreads();

  for (int t = tid; t < 576; t += 512) {
    const int half = t & 1;
    const int item = t >> 1;
    const int ochan = item % 9;
    const int pix = item / 9;
    const int c4base = half << 3;
    f32x4 acc = {0.f, 0.f, 0.f, 0.f};
#pragma unroll
    for (int pq = 0; pq < 9; ++pq) {
      const int p = pq / 3, q = pq - p * 3;
      const float4* xr = (const float4*)(xtile + (p * 34 + pix + q) * 68) + c4base;
      const float* wr = oW + (size_t)(pq * 64 + c4base * 4) * 9 + ochan;
#pragma unroll
      for (int c4 = 0; c4 < 8; ++c4) {
        const float4 v = xr[c4];
        acc.x += v.x * wr[(c4 * 4 + 0) * 9];
        acc.y += v.y * wr[(c4 * 4 + 1) * 9];
        acc.z += v.z * wr[(c4 * 4 + 2) * 9];
        acc.w += v.w * wr[(c4 * 4 + 3) * 9];
      }
    }
    float s = (acc.x + acc.y) + (acc.z + acc.w);
    s += __shfl_xor(s, 1);
    if (!half) offs_s[item] = s + ob[ochan];
  }
  __syncthreads();

  for (int it = tid; it < 32 * 9 * 16; it += 512) {
    const int c4 = it & 15;
    const int tmp = it >> 4;
    const int tap = tmp % 9;
    const int pix = tmp / 9;
    const int j = j0 + pix;
    const float off = offs_s[pix * 9 + tap];
    const int p = tap / 3;
    const int q = tap - p * 3;
    int yy = i + p - 1;
    yy = yy < 0 ? 0 : (yy > 127 ? 127 : yy);
    const float xf = (float)(j + q - 1) + off;
    const float x0f = floorf(xf);
    const float w1 = xf - x0f;
    int x0i = (int)x0f;
    x0i = x0i < 0 ? 0 : (x0i > 127 ? 127 : x0i);
    const int x1i = (x0i + 1 > 127) ? 127 : x0i + 1;
    const float4 s0 = ((const float4*)(xb + (((yy << 7) + x0i) << 6)))[c4];
    const float4 s1 = ((const float4*)(xb + (((yy << 7) + x1i) << 6)))[c4];
    const float w0 = 1.0f - w1;
    const int boff = (pix * 1152 + tap * 128 + c4 * 8) ^ ((pix & 7) << 4);
    uint2 pk;
    pk.x = (unsigned)f2bf(s0.x * w0 + s1.x * w1) |
           ((unsigned)f2bf(s0.y * w0 + s1.y * w1) << 16);
    pk.y = (unsigned)f2bf(s0.z * w0 + s1.z * w1) |
           ((unsigned)f2bf(s0.w * w0 + s1.w * w1) << 16);
    *(uint2*)(lds + boff) = pk;
  }
  __syncthreads();

  const int m = wv & 1;
  const int f0 = (wv >> 1) << 5;
  const int colf = lane & 15;
  const int q4 = lane >> 4;
  const int pixr = m * 16 + colf;
  f32x4 a0 = {0.f, 0.f, 0.f, 0.f}, a1 = a0;
  for (int ks = 0; ks < 18; ++ks) {
    const int aoff = (pixr * 1152 + ks * 64 + q4 * 16) ^ ((pixr & 7) << 4);
    const short8 af = *(const short8*)(lds + aoff);
    short8 bf0, bf1;
    const float* wp = cW + (size_t)(ks * 32 + q4 * 8) * 128 + f0 + colf;
#pragma unroll
    for (int jj = 0; jj < 8; ++jj) bf0[jj] = (short)f2bf(wp[jj * 128]);
#pragma unroll
    for (int jj = 0; jj < 8; ++jj) bf1[jj] = (short)f2bf(wp[jj * 128 + 16]);
    a0 = __builtin_amdgcn_mfma_f32_16x16x32_bf16(bf0, af, a0, 0, 0, 0);
    a1 = __builtin_amdgcn_mfma_f32_16x16x32_bf16(bf1, af, a1, 0, 0, 0);
  }

  const float cb0s = cb[f0 + colf];
  const float cb1s = cb[f0 + 16 + colf];
  float* obase = out + (((size_t)((b << 14) | (i << 7) | j0)) << 7);
#pragma unroll
  for (int reg = 0; reg < 4; ++reg) {
    float* r = obase + (size_t)(m * 16 + q4 * 4 + reg) * 128;
    r[f0 + colf] = a0[reg] + cb0s;
    r[f0 + 16 + colf] = a1[reg] + cb1s;
  }
}

extern "C" void kernel_launch(void* const* d_in, const int* in_sizes, int n_in,
                              void* d_out, int out_size, void* d_ws, size_t ws_size,
                              hipStream_t stream) {
  const float* x = (const float*)d_in[0];
  const float* oW = (const float*)d_in[1];
  const float* ob = (const float*)d_in[2];
  const float* cW = (const float*)d_in[3];
  const float* cb = (const float*)d_in[4];
  float* out = (float*)d_out;

  if (ws_size >= WS_SPLIT) {
    unsigned short* cWb = (unsigned short*)d_ws;
    float* offs = (float*)((char*)d_ws + OFFS_OFF);
    hipLaunchKernelGGL(offsets_pack_kernel, dim3(800), dim3(256), 0, stream,
                       x, oW, ob, cW, offs, cWb);
    hipLaunchKernelGGL(main_kernel, dim3(4096), dim3(512), 0, stream,
                       x, offs, cb, out, cWb);
  } else {
    hipLaunchKernelGGL(fused_deform_kernel, dim3(4096), dim3(512), 0, stream,
                       x, oW, ob, cW, cb, out);
  }
}

// Round 17
// 103.016 us; speedup vs baseline: 1.2576x; 1.1165x over previous
//
#include <hip/hip_runtime.h>
#include <hip/hip_bf16.h>

// Deformable 2D conv, split-kernel. B=8 H=128 W=128 C=64 F=128 K=3.
// KA: blocks 0..511 = offsets conv (R11-exact, proven ~46us); blocks
//     512..799 = cW->cWb bf16 pack [ks][q4][f][jj].
// KB: main, M=64: block = 64 pixels (half row), 512 thr = 8 waves,
//     XCD-swizzled. Halves per-output cWb L2 traffic (was 1.18GB total
//     ~34us at L2 BW -> 590MB). Wave w: m-tiles {(w&1)*16, 32+(w&1)*16},
//     f0=(w>>1)*32; 4 MFMA/ks with B-frags shared across m-tiles.
//     LDS: smpB 64x576 bf16 (73728B) + offw(2304) + gmeta(4608) = 80640B
//     -> 2 blocks/CU. Same XOR swizzle (conflict-free, verified 0).
// Fallback (small ws): fused kernel.
//
// MFMA 16x16x32 bf16 (m89/m91): A row=lane&15, k=8*(lane>>4)+j; B col same;
// D col=lane&15, row=4*(lane>>4)+reg.
// NOTE: offsets must stay fp32 (bf16 offsets flip floor() at the clamp
// discontinuities -> R5 failed at 2.39).

typedef __attribute__((ext_vector_type(8))) short short8;
typedef __attribute__((ext_vector_type(4))) float f32x4;

#define CWB_BYTES (18 * 4 * 128 * 8 * 2)  // 147456
#define OFFS_OFF  CWB_BYTES
#define OFFS_BYTES (131072 * 9 * 4)       // 4718592
#define WS_SPLIT  (CWB_BYTES + OFFS_BYTES)

__device__ __forceinline__ unsigned short f2bf(float f) {  // RNE
  union { float f; unsigned u; } v; v.f = f;
  unsigned r = v.u + 0x7fffu + ((v.u >> 16) & 1u);
  return (unsigned short)(r >> 16);
}

__device__ __forceinline__ unsigned pk2bf(float a, float b) {  // v_cvt_pk RNE
  __hip_bfloat162 h = __float22bfloat162_rn(make_float2(a, b));
  union { __hip_bfloat162 h; unsigned u; } c; c.h = h;
  return c.u;
}

// ---- KA: offsets (blocks 0..511, R11-exact) + pack (512..799) ------------
__global__ __launch_bounds__(256) void offsets_pack_kernel(
    const float* __restrict__ x, const float* __restrict__ oW,
    const float* __restrict__ ob, const float* __restrict__ cW,
    float* __restrict__ offs, unsigned short* __restrict__ cWb) {
  const int hw = blockIdx.x;
  if (hw >= 512) {  // pack: t = k*128 + f
    const int t = (hw - 512) * 256 + threadIdx.x;
    if (t < 73728) {
      const int k = t >> 7, f = t & 127;
      const int ks = k >> 5, q4 = (k >> 3) & 3, jj = k & 7;
      cWb[(size_t)(((ks * 4 + q4) * 128 + f) * 8 + jj)] = f2bf(cW[t]);
    }
    return;
  }
  const int logical = ((hw & 7) << 6) | (hw >> 3);  // XCD k -> batch k
  const int pix = logical * 256 + threadIdx.x;      // 0..131071
  const int j = pix & 127;
  const int i = (pix >> 7) & 127;
  const int b = pix >> 14;
  float acc[9];
#pragma unroll
  for (int t = 0; t < 9; ++t) acc[t] = ob[t];
  const float* xb = x + ((size_t)b << 20);
#pragma unroll
  for (int p = 0; p < 3; ++p) {
    const int yy = i + p - 1;
    if (yy < 0 || yy > 127) continue;  // zero padding
#pragma unroll
    for (int q = 0; q < 3; ++q) {
      const int xx = j + q - 1;
      if (xx < 0 || xx > 127) continue;
      const float4* xp = (const float4*)(xb + (((yy << 7) + xx) << 6));
      float4 v[16];
#pragma unroll
      for (int c4 = 0; c4 < 16; ++c4) v[c4] = xp[c4];
      const float* wp = oW + (p * 3 + q) * 576;  // wave-uniform -> sK$
#pragma unroll
      for (int c4 = 0; c4 < 16; ++c4) {
        const float* w = wp + c4 * 36;
#pragma unroll
        for (int t = 0; t < 9; ++t) acc[t] += v[c4].x * w[t];
#pragma unroll
        for (int t = 0; t < 9; ++t) acc[t] += v[c4].y * w[9 + t];
#pragma unroll
        for (int t = 0; t < 9; ++t) acc[t] += v[c4].z * w[18 + t];
#pragma unroll
        for (int t = 0; t < 9; ++t) acc[t] += v[c4].w * w[27 + t];
      }
    }
  }
  float* op = offs + (size_t)pix * 9;
#pragma unroll
  for (int t = 0; t < 9; ++t) op[t] = acc[t];
}

// ---- KB: gather + MFMA main conv, M=64 -----------------------------------
__global__ __launch_bounds__(512, 2) void main_kernel(
    const float* __restrict__ x, const float* __restrict__ offs,
    const float* __restrict__ cb, float* __restrict__ out,
    const unsigned short* __restrict__ cWb) {
  __shared__ __align__(16) char lds[64 * 576 * 2];  // 73728 B
  __shared__ float offw[576];   // w1 per (pix,tap)
  __shared__ int2 gmeta[576];   // g0,g1 byte offsets per (pix,tap)

  const int tid = threadIdx.x;
  const int hwbid = blockIdx.x;
  const int bid = ((hwbid & 7) << 8) | (hwbid >> 3);  // XCD k -> batch k
  const int j0 = (bid & 1) << 6;      // 2 strips of 64 px per row
  const int i = (bid >> 1) & 127;
  const int b = bid >> 8;
  const float* xb = x + ((size_t)b << 20);

  const int lane = tid & 63;
  const int wv = tid >> 6;

  // ---- meta: per-(pix,tap) gather metadata, computed once (576 items) ----
  const size_t base9 = ((size_t)(((b << 7) | i) << 7) | j0) * 9;
  for (int item = tid; item < 576; item += 512) {
    const int pix = item / 9;
    const int tap = item - pix * 9;
    const float off = offs[base9 + item];
    const int p = tap / 3;
    const int q = tap - p * 3;
    int yy = i + p - 1;
    yy = yy < 0 ? 0 : (yy > 127 ? 127 : yy);
    const float xf = (float)(j0 + pix + q - 1) + off;
    const float x0f = floorf(xf);
    const float w1 = xf - x0f;  // weight from UNclipped floor (matches ref)
    int x0i = (int)x0f;
    x0i = x0i < 0 ? 0 : (x0i > 127 ? 127 : x0i);
    const int x1i = (x0i + 1 > 127) ? 127 : x0i + 1;
    gmeta[item].x = ((yy << 7) + x0i) << 8;  // byte offset of 64-float row
    gmeta[item].y = ((yy << 7) + x1i) << 8;
    offw[item] = w1;
  }
  __syncthreads();

  // ---- Phase 1: gather; 6 batches x (3 items -> 6 loads) ----
#pragma unroll
  for (int batch = 0; batch < 6; ++batch) {
    int a0_[3], a1_[3], sb[3];
    float sw1[3];
#pragma unroll
    for (int s = 0; s < 3; ++s) {
      const int idx = tid + (batch * 3 + s) * 512;
      const int c4 = idx & 15;
      const int pair = idx >> 4;        // 0..575
      const int2 g = gmeta[pair];
      sw1[s] = offw[pair];
      a0_[s] = g.x + (c4 << 4);
      a1_[s] = g.y + (c4 << 4);
      const int pix8 = (pair / 9) & 7;
      sb[s] = ((pair << 7) + (c4 << 3)) ^ (pix8 << 4);
    }
    float4 s0[3], s1[3];
#pragma unroll
    for (int s = 0; s < 3; ++s) {
      s0[s] = *(const float4*)((const char*)xb + a0_[s]);
      s1[s] = *(const float4*)((const char*)xb + a1_[s]);
    }
    asm volatile("" :: "v"(s0[0].x), "v"(s0[1].x), "v"(s0[2].x),
                       "v"(s1[0].x), "v"(s1[1].x), "v"(s1[2].x));
    __builtin_amdgcn_sched_barrier(0);
#pragma unroll
    for (int s = 0; s < 3; ++s) {
      const float w1 = sw1[s];
      uint2 pk;
      pk.x = pk2bf(s0[s].x + w1 * (s1[s].x - s0[s].x),
                   s0[s].y + w1 * (s1[s].y - s0[s].y));
      pk.y = pk2bf(s0[s].z + w1 * (s1[s].z - s0[s].z),
                   s0[s].w + w1 * (s1[s].w - s0[s].w));
      *(uint2*)(lds + sb[s]) = pk;
    }
  }
  __syncthreads();

  // ---- Phase 2: MFMA. Wave w: m-tiles {(w&1)*16, +32}, f0=(w>>1)*32 ----
  const int f0 = (wv >> 1) << 5;
  const int colf = lane & 15;
  const int q4 = lane >> 4;
  const int pixr0 = ((wv & 1) << 4) + colf;   // m-tile A
  // m-tile B is pixr0 + 32: same (pix&7) -> same XOR class, +36864 bytes
  f32x4 a00 = {0.f, 0.f, 0.f, 0.f}, a01 = a00, a10 = a00, a11 = a00;
  short8 bf0, bf1;
  {
    const unsigned short* wb = cWb + (size_t)((q4 * 128 + f0 + colf) * 8);
    bf0 = *(const short8*)wb;
    bf1 = *(const short8*)(wb + 128);
  }
  for (int ks = 0; ks < 18; ++ks) {
    const int aoff = (pixr0 * 1152 + ks * 64 + q4 * 16) ^ ((pixr0 & 7) << 4);
    const short8 af0 = *(const short8*)(lds + aoff);
    const short8 af1 = *(const short8*)(lds + aoff + 32 * 1152);
    short8 nb0, nb1;
    if (ks < 17) {
      const unsigned short* wn =
          cWb + (size_t)((((ks + 1) * 4 + q4) * 128 + f0 + colf) * 8);
      nb0 = *(const short8*)wn;
      nb1 = *(const short8*)(wn + 128);
    }
    a00 = __builtin_amdgcn_mfma_f32_16x16x32_bf16(bf0, af0, a00, 0, 0, 0);
    a01 = __builtin_amdgcn_mfma_f32_16x16x32_bf16(bf1, af0, a01, 0, 0, 0);
    a10 = __builtin_amdgcn_mfma_f32_16x16x32_bf16(bf0, af1, a10, 0, 0, 0);
    a11 = __builtin_amdgcn_mfma_f32_16x16x32_bf16(bf1, af1, a11, 0, 0, 0);
    if (ks < 17) { bf0 = nb0; bf1 = nb1; }
  }
  __syncthreads();  // phase-2 LDS reads done; reuse lds for out staging

  // ---- Epilogue: stage [64 pix][132] fp32, then coalesced stores ----
  float* const outS = (float*)lds;
  {
    const float4 cb0 = *(const float4*)(cb + f0 + q4 * 4);
    const float4 cb1 = *(const float4*)(cb + f0 + 16 + q4 * 4);
    float4 r;
    r.x = a00[0] + cb0.x; r.y = a00[1] + cb0.y;
    r.z = a00[2] + cb0.z; r.w = a00[3] + cb0.w;
    *(float4*)(outS + pixr0 * 132 + f0 + q4 * 4) = r;
    r.x = a01[0] + cb1.x; r.y = a01[1] + cb1.y;
    r.z = a01[2] + cb1.z; r.w = a01[3] + cb1.w;
    *(float4*)(outS + pixr0 * 132 + f0 + 16 + q4 * 4) = r;
    r.x = a10[0] + cb0.x; r.y = a10[1] + cb0.y;
    r.z = a10[2] + cb0.z; r.w = a10[3] + cb0.w;
    *(float4*)(outS + (pixr0 + 32) * 132 + f0 + q4 * 4) = r;
    r.x = a11[0] + cb1.x; r.y = a11[1] + cb1.y;
    r.z = a11[2] + cb1.z; r.w = a11[3] + cb1.w;
    *(float4*)(outS + (pixr0 + 32) * 132 + f0 + 16 + q4 * 4) = r;
  }
  __syncthreads();
  float4* og = (float4*)(out + (((size_t)((b << 14) | (i << 7) | j0)) << 7));
#pragma unroll
  for (int r = 0; r < 4; ++r) {
    const int f4i = r * 512 + tid;
    const int pp = f4i >> 5, ff = f4i & 31;
    og[pp * 32 + ff] = *(const float4*)(outS + pp * 132 + ff * 4);
  }
}

// ---- Fallback: fused kernel (small ws) ----
__global__ __launch_bounds__(512, 8) void fused_deform_kernel(
    const float* __restrict__ x, const float* __restrict__ oW,
    const float* __restrict__ ob, const float* __restrict__ cW,
    const float* __restrict__ cb, float* __restrict__ out) {
  __shared__ __align__(16) char lds[32 * 576 * 2];
  __shared__ float offs_s[288];
  float* const xtile = (float*)lds;  // [102 rows][stride 68]

  const int tid = threadIdx.x;
  const int bid = blockIdx.x;
  const int j0 = (bid & 3) << 5;
  const int i = (bid >> 2) & 127;
  const int b = bid >> 9;
  const float* xb = x + ((size_t)b << 20);
  const int lane = tid & 63;
  const int wv = tid >> 6;

  for (int t = tid; t < 3 * 34 * 16; t += 512) {
    const int c4 = t & 15;
    const int cc = (t >> 4) % 34;
    const int r = (t >> 4) / 34;
    const int row = i + r - 1;
    const int col = j0 + cc - 1;
    float4 v = make_float4(0.f, 0.f, 0.f, 0.f);
    if (row >= 0 && row <= 127 && col >= 0 && col <= 127)
      v = ((const float4*)(xb + (((row << 7) + col) << 6)))[c4];
    *(float4*)(xtile + (r * 34 + cc) * 68 + c4 * 4) = v;
  }
  __syncthreads();

  for (int t = tid; t < 576; t += 512) {
    const int half = t & 1;
    const int item = t >> 1;
    const int ochan = item % 9;
    const int pix = item / 9;
    const int c4base = half << 3;
    f32x4 acc = {0.f, 0.f, 0.f, 0.f};
#pragma unroll
    for (int pq = 0; pq < 9; ++pq) {
      const int p = pq / 3, q = pq - p * 3;
      const float4* xr = (const float4*)(xtile + (p * 34 + pix + q) * 68) + c4base;
      const float* wr = oW + (size_t)(pq * 64 + c4base * 4) * 9 + ochan;
#pragma unroll
      for (int c4 = 0; c4 < 8; ++c4) {
        const float4 v = xr[c4];
        acc.x += v.x * wr[(c4 * 4 + 0) * 9];
        acc.y += v.y * wr[(c4 * 4 + 1) * 9];
        acc.z += v.z * wr[(c4 * 4 + 2) * 9];
        acc.w += v.w * wr[(c4 * 4 + 3) * 9];
      }
    }
    float s = (acc.x + acc.y) + (acc.z + acc.w);
    s += __shfl_xor(s, 1);
    if (!half) offs_s[item] = s + ob[ochan];
  }
  __syncthreads();

  for (int it = tid; it < 32 * 9 * 16; it += 512) {
    const int c4 = it & 15;
    const int tmp = it >> 4;
    const int tap = tmp % 9;
    const int pix = tmp / 9;
    const int j = j0 + pix;
    const float off = offs_s[pix * 9 + tap];
    const int p = tap / 3;
    const int q = tap - p * 3;
    int yy = i + p - 1;
    yy = yy < 0 ? 0 : (yy > 127 ? 127 : yy);
    const float xf = (float)(j + q - 1) + off;
    const float x0f = floorf(xf);
    const float w1 = xf - x0f;
    int x0i = (int)x0f;
    x0i = x0i < 0 ? 0 : (x0i > 127 ? 127 : x0i);
    const int x1i = (x0i + 1 > 127) ? 127 : x0i + 1;
    const float4 s0 = ((const float4*)(xb + (((yy << 7) + x0i) << 6)))[c4];
    const float4 s1 = ((const float4*)(xb + (((yy << 7) + x1i) << 6)))[c4];
    const float w0 = 1.0f - w1;
    const int boff = (pix * 1152 + tap * 128 + c4 * 8) ^ ((pix & 7) << 4);
    uint2 pk;
    pk.x = (unsigned)f2bf(s0.x * w0 + s1.x * w1) |
           ((unsigned)f2bf(s0.y * w0 + s1.y * w1) << 16);
    pk.y = (unsigned)f2bf(s0.z * w0 + s1.z * w1) |
           ((unsigned)f2bf(s0.w * w0 + s1.w * w1) << 16);
    *(uint2*)(lds + boff) = pk;
  }
  __syncthreads();

  const int m = wv & 1;
  const int f0 = (wv >> 1) << 5;
  const int colf = lane & 15;
  const int q4 = lane >> 4;
  const int pixr = m * 16 + colf;
  f32x4 a0 = {0.f, 0.f, 0.f, 0.f}, a1 = a0;
  for (int ks = 0; ks < 18; ++ks) {
    const int aoff = (pixr * 1152 + ks * 64 + q4 * 16) ^ ((pixr & 7) << 4);
    const short8 af = *(const short8*)(lds + aoff);
    short8 bf0, bf1;
    const float* wp = cW + (size_t)(ks * 32 + q4 * 8) * 128 + f0 + colf;
#pragma unroll
    for (int jj = 0; jj < 8; ++jj) bf0[jj] = (short)f2bf(wp[jj * 128]);
#pragma unroll
    for (int jj = 0; jj < 8; ++jj) bf1[jj] = (short)f2bf(wp[jj * 128 + 16]);
    a0 = __builtin_amdgcn_mfma_f32_16x16x32_bf16(bf0, af, a0, 0, 0, 0);
    a1 = __builtin_amdgcn_mfma_f32_16x16x32_bf16(bf1, af, a1, 0, 0, 0);
  }

  const float cb0s = cb[f0 + colf];
  const float cb1s = cb[f0 + 16 + colf];
  float* obase = out + (((size_t)((b << 14) | (i << 7) | j0)) << 7);
#pragma unroll
  for (int reg = 0; reg < 4; ++reg) {
    float* r = obase + (size_t)(m * 16 + q4 * 4 + reg) * 128;
    r[f0 + colf] = a0[reg] + cb0s;
    r[f0 + 16 + colf] = a1[reg] + cb1s;
  }
}

extern "C" void kernel_launch(void* const* d_in, const int* in_sizes, int n_in,
                              void* d_out, int out_size, void* d_ws, size_t ws_size,
                              hipStream_t stream) {
  const float* x = (const float*)d_in[0];
  const float* oW = (const float*)d_in[1];
  const float* ob = (const float*)d_in[2];
  const float* cW = (const float*)d_in[3];
  const float* cb = (const float*)d_in[4];
  float* out = (float*)d_out;

  if (ws_size >= WS_SPLIT) {
    unsigned short* cWb = (unsigned short*)d_ws;
    float* offs = (float*)((char*)d_ws + OFFS_OFF);
    hipLaunchKernelGGL(offsets_pack_kernel, dim3(800), dim3(256), 0, stream,
                       x, oW, ob, cW, offs, cWb);
    hipLaunchKernelGGL(main_kernel, dim3(2048), dim3(512), 0, stream,
                       x, offs, cb, out, cWb);
  } else {
    hipLaunchKernelGGL(fused_deform_kernel, dim3(4096), dim3(512), 0, stream,
                       x, oW, ob, cW, cb, out);
  }
}